// Round 4
// baseline (103.367 us; speedup 1.0000x reference)
//
#include <hip/hip_runtime.h>
#include <math.h>

// HyperpriorDensity: per-channel tiny MLP CDF at x±0.5.
// out = max(0.5*|tanh(f_c(x+0.5)/2) - tanh(f_c(x-0.5)/2)|, 1e-9)
// identity |sigmoid(a)-sigmoid(b)| = 0.5|tanh(a/2)-tanh(b/2)| replaces the
// reference's sign/stop_gradient stabilization exactly (sign-invariant).
//
// Two kernels:
//  1) hp_prep: fold per-channel params (softplus(H), tanh(a), b) into
//     d_ws[c*48 + i] — 320*44 values, recomputed every launch (ws re-poisoned).
//  2) hp_main: per (n,c) slab of 1024 elems, 256 thr * float4. Params read via
//     wave-uniform address -> scalar loads (SGPRs); no LDS, no local arrays.

constexpr int HW   = 1024;
constexpr int NPAR = 44;    // packed params per channel
constexpr int PSTR = 48;    // padded stride (16B-aligned blocks)
constexpr float MINL = 1e-9f;

__device__ __forceinline__ float softplus_f(float v) {
    return fmaxf(v, 0.0f) + log1pf(expf(-fabsf(v)));
}

// stable fast tanh: e = exp(-2|u|) in (0,1], tanh = sign * (1-e)/(1+e)
__device__ __forceinline__ float fast_tanh(float u) {
    float e = __expf(-2.0f * fabsf(u));
    float t = __fdividef(1.0f - e, 1.0f + e);
    return copysignf(t, u);
}

__global__ __launch_bounds__(256)
void hp_prep(const float* __restrict__ H0, const float* __restrict__ a0, const float* __restrict__ b0,
             const float* __restrict__ H1, const float* __restrict__ a1, const float* __restrict__ b1,
             const float* __restrict__ H2, const float* __restrict__ a2, const float* __restrict__ b2,
             const float* __restrict__ H3, const float* __restrict__ a3, const float* __restrict__ b3,
             float* __restrict__ P, int C)
{
    int t = blockIdx.x * 256 + threadIdx.x;
    if (t >= C * NPAR) return;
    int c = t / NPAR;
    int i = t - c * NPAR;
    float v;
    if (i < 24) {
        float h;
        if      (i < 3)  h = H0[c * 3 + i];
        else if (i < 12) h = H1[c * 9 + (i - 3)];
        else if (i < 21) h = H2[c * 9 + (i - 12)];
        else             h = H3[c * 3 + (i - 21)];
        v = softplus_f(h);
    } else if (i < 34) {
        int j = i - 24; float a;
        if      (j < 3) a = a0[c * 3 + j];
        else if (j < 6) a = a1[c * 3 + (j - 3)];
        else if (j < 9) a = a2[c * 3 + (j - 6)];
        else            a = a3[c];
        v = tanhf(a);
    } else {
        int j = i - 34; float b;
        if      (j < 3) b = b0[c * 3 + j];
        else if (j < 6) b = b1[c * 3 + (j - 3)];
        else if (j < 9) b = b2[c * 3 + (j - 6)];
        else            b = b3[c];
        v = b;
    }
    P[c * PSTR + i] = v;
}

__global__ __launch_bounds__(256)
void hp_main(const float* __restrict__ x, const float* __restrict__ P,
             float* __restrict__ out, int C)
{
    const int c   = blockIdx.x;
    const int n   = blockIdx.y;
    const int tid = threadIdx.x;

    // wave-uniform base -> compiler emits s_load; params live in SGPRs
    const float* __restrict__ q = P + (size_t)c * PSTR;
    const float k0 = q[0],  k1 = q[1],  k2 = q[2],  k3 = q[3],  k4 = q[4];
    const float k5 = q[5],  k6 = q[6],  k7 = q[7],  k8 = q[8],  k9 = q[9];
    const float k10 = q[10], k11 = q[11], k12 = q[12], k13 = q[13], k14 = q[14];
    const float k15 = q[15], k16 = q[16], k17 = q[17], k18 = q[18], k19 = q[19];
    const float k20 = q[20], k21 = q[21], k22 = q[22], k23 = q[23];
    const float g0 = q[24], g1 = q[25], g2 = q[26], g3 = q[27], g4 = q[28];
    const float g5 = q[29], g6 = q[30], g7 = q[31], g8 = q[32], g9 = q[33];
    const float c0 = q[34], c1 = q[35], c2 = q[36], c3 = q[37], c4 = q[38];
    const float c5 = q[39], c6 = q[40], c7 = q[41], c8 = q[42], c9 = q[43];

    const bool gated = (g0 != 0.f) | (g1 != 0.f) | (g2 != 0.f) | (g3 != 0.f) |
                       (g4 != 0.f) | (g5 != 0.f) | (g6 != 0.f) | (g7 != 0.f) |
                       (g8 != 0.f) | (g9 != 0.f);

    auto cdfU = [&](float u) -> float {          // ungated: all gate coeffs == 0
        float y0 = fmaf(k0, u, c0);
        float y1 = fmaf(k1, u, c1);
        float y2 = fmaf(k2, u, c2);
        float z0 = fmaf(k3, y0, fmaf(k4,  y1, fmaf(k5,  y2, c3)));
        float z1 = fmaf(k6, y0, fmaf(k7,  y1, fmaf(k8,  y2, c4)));
        float z2 = fmaf(k9, y0, fmaf(k10, y1, fmaf(k11, y2, c5)));
        float w0 = fmaf(k12, z0, fmaf(k13, z1, fmaf(k14, z2, c6)));
        float w1 = fmaf(k15, z0, fmaf(k16, z1, fmaf(k17, z2, c7)));
        float w2 = fmaf(k18, z0, fmaf(k19, z1, fmaf(k20, z2, c8)));
        float s  = fmaf(k21, w0, fmaf(k22, w1, fmaf(k23, w2, c9)));
        return fast_tanh(0.5f * s);
    };
    auto cdfG = [&](float u) -> float {          // general gated path
        float y0 = fmaf(k0, u, c0);
        float y1 = fmaf(k1, u, c1);
        float y2 = fmaf(k2, u, c2);
        y0 = fmaf(g0, fast_tanh(y0), y0);
        y1 = fmaf(g1, fast_tanh(y1), y1);
        y2 = fmaf(g2, fast_tanh(y2), y2);
        float z0 = fmaf(k3, y0, fmaf(k4,  y1, fmaf(k5,  y2, c3)));
        float z1 = fmaf(k6, y0, fmaf(k7,  y1, fmaf(k8,  y2, c4)));
        float z2 = fmaf(k9, y0, fmaf(k10, y1, fmaf(k11, y2, c5)));
        z0 = fmaf(g3, fast_tanh(z0), z0);
        z1 = fmaf(g4, fast_tanh(z1), z1);
        z2 = fmaf(g5, fast_tanh(z2), z2);
        float w0 = fmaf(k12, z0, fmaf(k13, z1, fmaf(k14, z2, c6)));
        float w1 = fmaf(k15, z0, fmaf(k16, z1, fmaf(k17, z2, c7)));
        float w2 = fmaf(k18, z0, fmaf(k19, z1, fmaf(k20, z2, c8)));
        w0 = fmaf(g6, fast_tanh(w0), w0);
        w1 = fmaf(g7, fast_tanh(w1), w1);
        w2 = fmaf(g8, fast_tanh(w2), w2);
        float s = fmaf(k21, w0, fmaf(k22, w1, fmaf(k23, w2, c9)));
        s = fmaf(g9, fast_tanh(s), s);
        return fast_tanh(0.5f * s);
    };

    const size_t base = ((size_t)n * (size_t)C + (size_t)c) * (size_t)HW;
    const float4 v = reinterpret_cast<const float4*>(x + base)[tid];
    float4 r;
    if (!gated) {
        r.x = fmaxf(0.5f * fabsf(cdfU(v.x + 0.5f) - cdfU(v.x - 0.5f)), MINL);
        r.y = fmaxf(0.5f * fabsf(cdfU(v.y + 0.5f) - cdfU(v.y - 0.5f)), MINL);
        r.z = fmaxf(0.5f * fabsf(cdfU(v.z + 0.5f) - cdfU(v.z - 0.5f)), MINL);
        r.w = fmaxf(0.5f * fabsf(cdfU(v.w + 0.5f) - cdfU(v.w - 0.5f)), MINL);
    } else {
        r.x = fmaxf(0.5f * fabsf(cdfG(v.x + 0.5f) - cdfG(v.x - 0.5f)), MINL);
        r.y = fmaxf(0.5f * fabsf(cdfG(v.y + 0.5f) - cdfG(v.y - 0.5f)), MINL);
        r.z = fmaxf(0.5f * fabsf(cdfG(v.z + 0.5f) - cdfG(v.z - 0.5f)), MINL);
        r.w = fmaxf(0.5f * fabsf(cdfG(v.w + 0.5f) - cdfG(v.w - 0.5f)), MINL);
    }
    reinterpret_cast<float4*>(out + base)[tid] = r;
}

extern "C" void kernel_launch(void* const* d_in, const int* in_sizes, int n_in,
                              void* d_out, int out_size, void* d_ws, size_t ws_size,
                              hipStream_t stream) {
    const float* x  = (const float*)d_in[0];
    const float* H0 = (const float*)d_in[1];
    const float* a0 = (const float*)d_in[2];
    const float* b0 = (const float*)d_in[3];
    const float* H1 = (const float*)d_in[4];
    const float* a1 = (const float*)d_in[5];
    const float* b1 = (const float*)d_in[6];
    const float* H2 = (const float*)d_in[7];
    const float* a2 = (const float*)d_in[8];
    const float* b2 = (const float*)d_in[9];
    const float* H3 = (const float*)d_in[10];
    const float* a3 = (const float*)d_in[11];
    const float* b3 = (const float*)d_in[12];
    float* out = (float*)d_out;
    float* P   = (float*)d_ws;                 // C*48 floats

    const int C = in_sizes[1] / 3;             // H0 is (C,3,1)
    const int N = in_sizes[0] / (C * HW);      // x is (N,C,32,32)

    const int prep_items = C * NPAR;
    hipLaunchKernelGGL(hp_prep, dim3((prep_items + 255) / 256), dim3(256), 0, stream,
                       H0, a0, b0, H1, a1, b1, H2, a2, b2, H3, a3, b3, P, C);
    hipLaunchKernelGGL(hp_main, dim3(C, N), dim3(256), 0, stream,
                       x, P, out, C);
}